// Round 2
// baseline (481.900 us; speedup 1.0000x reference)
//
#include <hip/hip_runtime.h>

typedef __bf16 bf16x8 __attribute__((ext_vector_type(8)));
typedef __bf16 bf16x4 __attribute__((ext_vector_type(4)));
typedef float  f32x4  __attribute__((ext_vector_type(4)));

// ---- workspace layout (in __bf16 elements) ----
constexpr int WS_AS0 = 0;        // A_static layer0: [64][64]
constexpr int WS_AS1 = 4096;     // A_static layer1
constexpr int WS_MT0 = 8192;     // MT0 = ph0^T@th0/sqrt(128), [256][256] bf16
constexpr int WS_MT1 = 73728;
constexpr int WS_FC0 = 139264;   // fc0 bf16 [256][256]
constexpr int WS_FC1 = 204800;   // end 270336 elems = 540672 B

static __device__ __forceinline__ f32x4 mfma16(bf16x8 a, bf16x8 b, f32x4 c) {
    return __builtin_amdgcn_mfma_f32_16x16x32_bf16(a, b, c, 0, 0, 0);
}

// ---------- single prep kernel: adj softmax | MT gemm | fc cast ----------
// grid: [0,32) adj rows (1 wave/row) | [32,544) MT (block=e,layer) | [544,800) fc
__global__ void prep_all(const float* __restrict__ adj0, const float* __restrict__ adj1,
                         const float* __restrict__ th0,  const float* __restrict__ ph0,
                         const float* __restrict__ th1,  const float* __restrict__ ph1,
                         const float* __restrict__ fc0,  const float* __restrict__ fc1,
                         __bf16* __restrict__ wsb) {
    const int blk = blockIdx.x, tid = threadIdx.x;
    if (blk < 32) {
        const int w = tid >> 6, lane = tid & 63;
        const int row = blk * 4 + w;              // 0..127
        const int layer = row >> 6, r = row & 63;
        const float* a = (layer ? adj1 : adj0) + r * 64;
        const float v = a[lane];
        float mx = v;
        #pragma unroll
        for (int m = 1; m < 64; m <<= 1) mx = fmaxf(mx, __shfl_xor(mx, m));
        float e = __expf(v - mx), sum = e;
        #pragma unroll
        for (int m = 1; m < 64; m <<= 1) sum += __shfl_xor(sum, m);
        wsb[(layer ? WS_AS1 : WS_AS0) + r * 64 + lane] = (__bf16)(e / sum);
    } else if (blk < 544) {
        const int e = (blk - 32) & 255, layer = (blk - 32) >> 8, d = tid;
        const float* th = layer ? th1 : th0;
        const float* ph = layer ? ph1 : ph0;
        float s = 0.f;
        #pragma unroll 8
        for (int h = 0; h < 128; ++h) s += ph[h * 256 + e] * th[h * 256 + d];
        wsb[(layer ? WS_MT1 : WS_MT0) + e * 256 + d] = (__bf16)(s * 0.088388347648318447f);
    } else {
        const int i = (blk - 544) * 512 + tid * 2;    // 0..131070 step 2
        if (i < 65536) {
            wsb[WS_FC0 + i]     = (__bf16)fc0[i];
            wsb[WS_FC0 + i + 1] = (__bf16)fc0[i + 1];
        } else {
            wsb[WS_FC1 + i - 65536] = (__bf16)fc1[i - 65536];
            wsb[WS_FC1 + i - 65535] = (__bf16)fc1[i - 65535];
        }
    }
}

// ---------- fused 2-layer GCN: persistent blocks, 4 batch elements each ----------
// grid 512 x 512 threads (8 waves), LDS 80384 B -> 2 blocks/CU, all-resident.
// Per element: P1(LN from prefetched regs) | A(t+z merged per-jm, z in regs) |
// P3(scores/softmax) | zT-write (+prefetch next graph slice) | P5(A_hat@zT +
// LN/leaky or store).
__global__ __launch_bounds__(512, 4) void fused_gcn(
    const float* __restrict__ graph,
    const float* __restrict__ ln_in_g, const float* __restrict__ ln_in_b,
    const __bf16* __restrict__ wsb,
    const float* __restrict__ fcb0, const float* __restrict__ ln0_g,
    const float* __restrict__ ln0_b, const float* __restrict__ fcb1,
    float* __restrict__ outp)
{
    constexpr int XN_S = 264;   // xn / t row stride (bf16), 528 B = 33*16B (odd granule)
    constexpr int ZT_S = 72;    // zT row stride: 144 B
    constexpr int AH_S = 72;    // A_hat row stride

    __shared__ __align__(16) __bf16 sXn[64 * XN_S];   // 33792 B  (xn, persistent per layer)
    __shared__ __align__(16) __bf16 sR1[256 * ZT_S];  // 36864 B  (t[64][XN_S], then zT[256][72])
    __shared__ __align__(16) __bf16 sAh[64 * AH_S];   //  9216 B  (As staged, then A_hat)
    __shared__ float sRed[128];                       //   512 B

    const int tid = threadIdx.x;
    const int w = tid >> 6, lane = tid & 63;
    const int l15 = lane & 15, qd = lane >> 4;
    const int r8 = tid >> 3, ci8 = (tid & 7) * 32;    // P1/prefetch row & col base

    // ---- prefetch element 0's graph slice into registers
    f32x4 gv[8];
    {
        const float* gp = graph + (size_t)blockIdx.x * 16384 + r8 * 256 + ci8;
        #pragma unroll
        for (int j = 0; j < 8; ++j) gv[j] = *(const f32x4*)(gp + j * 4);
    }

    #pragma unroll 1
    for (int it = 0; it < 4; ++it) {
        const int b = blockIdx.x + it * 512;

        // ---- P1: LayerNorm(graph[b]) -> sXn (bf16). 8 threads per row, from gv regs.
        {
            if (tid < 128) sRed[tid] = 0.f;
            float s = 0.f, s2 = 0.f;
            #pragma unroll
            for (int j = 0; j < 8; ++j)
                #pragma unroll
                for (int e = 0; e < 4; ++e) { s += gv[j][e]; s2 += gv[j][e] * gv[j][e]; }
            #pragma unroll
            for (int m = 1; m <= 4; m <<= 1) { s += __shfl_xor(s, m); s2 += __shfl_xor(s2, m); }
            const float mean = s * (1.f / 256.f);
            const float var  = s2 * (1.f / 256.f) - mean * mean;
            const float rstd = rsqrtf(var + 1e-5f);
            #pragma unroll
            for (int j = 0; j < 8; ++j) {
                f32x4 gg = *(const f32x4*)(ln_in_g + ci8 + j * 4);
                f32x4 bb = *(const f32x4*)(ln_in_b + ci8 + j * 4);
                bf16x4 pk;
                #pragma unroll
                for (int e = 0; e < 4; ++e)
                    pk[e] = (__bf16)((gv[j][e] - mean) * rstd * gg[e] + bb[e]);
                *(bf16x4*)&sXn[r8 * XN_S + ci8 + j * 4] = pk;
            }
        }
        __syncthreads();                                   // b1

        #pragma unroll 1
        for (int layer = 0; layer < 2; ++layer) {
            const __bf16* As  = wsb + (layer ? WS_AS1 : WS_AS0);
            const __bf16* mtw = wsb + (layer ? WS_MT1 : WS_MT0);
            const __bf16* fcw = wsb + (layer ? WS_FC1 : WS_FC0);
            const float*  fcb = layer ? fcb1 : fcb0;

            bf16x4 zpk[4][2];   // packed z slice, lives across the next two barriers

            // ---- Phase A: t = xn@M AND z = xn@fc^T sharing sXn reads, split by jm
            //      to cap register pressure. t -> sR1 (row-major t[node][e]);
            //      z stays in registers. Stage As -> sAh.
            {
                {   // stage A_static into sAh (one b128 per thread)
                    const int rr = tid >> 3, c8 = (tid & 7) * 8;
                    *(bf16x8*)&sAh[rr * AH_S + c8] = *(const bf16x8*)(As + rr * 64 + c8);
                }
                #pragma unroll
                for (int jm = 0; jm < 2; ++jm) {
                    const int row = w * 32 + jm * 16 + l15;   // e-row (mtw) == o-row (fcw)
                    f32x4 tacc[4], zacc[4];
                    #pragma unroll
                    for (int i = 0; i < 4; ++i) {
                        tacc[i] = (f32x4){0.f, 0.f, 0.f, 0.f};
                        zacc[i] = (f32x4){0.f, 0.f, 0.f, 0.f};
                    }
                    #pragma unroll
                    for (int kk = 0; kk < 8; ++kk) {
                        const int co = kk * 32 + qd * 8;
                        bf16x8 amt = *(const bf16x8*)(mtw + row * 256 + co);
                        bf16x8 afc = *(const bf16x8*)(fcw + row * 256 + co);
                        #pragma unroll
                        for (int nt = 0; nt < 4; ++nt) {
                            bf16x8 bx = *(const bf16x8*)&sXn[(nt * 16 + l15) * XN_S + co];
                            tacc[nt] = mfma16(amt, bx, tacc[nt]);   // C[e][node]
                            zacc[nt] = mfma16(bx, afc, zacc[nt]);   // C[node][o]
                        }
                    }
                    // write t row-major (lane holds 4 consecutive e at node nt*16+l15)
                    #pragma unroll
                    for (int nt = 0; nt < 4; ++nt) {
                        bf16x4 pk;
                        #pragma unroll
                        for (int r = 0; r < 4; ++r) pk[r] = (__bf16)tacc[nt][r];
                        *(bf16x4*)&sR1[(nt * 16 + l15) * XN_S + (w * 2 + jm) * 16 + qd * 4] = pk;
                    }
                    // pack z to bf16 regs (deferred LDS write until t is dead)
                    #pragma unroll
                    for (int nt = 0; nt < 4; ++nt)
                        #pragma unroll
                        for (int r = 0; r < 4; ++r)
                            zpk[nt][jm][r] = (__bf16)zacc[nt][r];
                }
            }
            __syncthreads();                               // b2

            // ---- P3 (waves 0-3): scores = t@xn^T (K=256) -> softmax -> +As
            if (w < 4) {
                const int mb = w * 16;
                bf16x8 at[8];
                #pragma unroll
                for (int kk = 0; kk < 8; ++kk)
                    at[kk] = *(const bf16x8*)&sR1[(mb + l15) * XN_S + kk * 32 + qd * 8];
                f32x4 sc[4];
                #pragma unroll
                for (int nt = 0; nt < 4; ++nt) sc[nt] = (f32x4){0.f, 0.f, 0.f, 0.f};
                #pragma unroll
                for (int nt = 0; nt < 4; ++nt)
                    #pragma unroll
                    for (int kk = 0; kk < 8; ++kk) {
                        bf16x8 bx = *(const bf16x8*)&sXn[(nt * 16 + l15) * XN_S + kk * 32 + qd * 8];
                        sc[nt] = mfma16(at[kk], bx, sc[nt]);
                    }
                #pragma unroll
                for (int r = 0; r < 4; ++r) {
                    float v[4];
                    #pragma unroll
                    for (int nt = 0; nt < 4; ++nt) v[nt] = sc[nt][r];
                    float mx = fmaxf(fmaxf(v[0], v[1]), fmaxf(v[2], v[3]));
                    #pragma unroll
                    for (int m = 1; m <= 8; m <<= 1) mx = fmaxf(mx, __shfl_xor(mx, m));
                    float e[4], sum = 0.f;
                    #pragma unroll
                    for (int nt = 0; nt < 4; ++nt) { e[nt] = __expf(v[nt] - mx); sum += e[nt]; }
                    #pragma unroll
                    for (int m = 1; m <= 8; m <<= 1) sum += __shfl_xor(sum, m);
                    const float inv = 1.f / sum;
                    const int row = mb + qd * 4 + r;
                    #pragma unroll
                    for (int nt = 0; nt < 4; ++nt) {
                        const int col = nt * 16 + l15;
                        const float as = (float)sAh[row * AH_S + col];   // staged As
                        sAh[row * AH_S + col] = (__bf16)(e[nt] * inv + as);
                    }
                }
            }
            __syncthreads();                               // b3 (t dead; zT region free)

            // ---- zT write from registers (all 8 waves) + next-element graph prefetch
            {
                #pragma unroll
                for (int jm = 0; jm < 2; ++jm) {
                    const int o = w * 32 + jm * 16 + l15;
                    #pragma unroll
                    for (int nt = 0; nt < 4; ++nt)
                        *(bf16x4*)&sR1[o * ZT_S + nt * 16 + qd * 4] = zpk[nt][jm];
                }
            }
            if (layer == 1 && it < 3) {
                const float* gp = graph + (size_t)(b + 512) * 16384 + r8 * 256 + ci8;
                #pragma unroll
                for (int j = 0; j < 8; ++j) gv[j] = *(const f32x4*)(gp + j * 4);
            }
            __syncthreads();                               // b4

            // ---- P5: out = A_hat @ zT + fcb; fused LN+leaky (layer0) or store.
            {
                const int mb = (w & 3) * 16, ng = w >> 2;
                bf16x8 aa[2];
                #pragma unroll
                for (int kk = 0; kk < 2; ++kk)
                    aa[kk] = *(const bf16x8*)&sAh[(mb + l15) * AH_S + kk * 32 + qd * 8];
                f32x4 oacc[8];
                #pragma unroll
                for (int j = 0; j < 8; ++j) {
                    const int o = ng * 128 + j * 16 + l15;
                    f32x4 acc = {0.f, 0.f, 0.f, 0.f};
                    #pragma unroll
                    for (int kk = 0; kk < 2; ++kk) {
                        bf16x8 bb = *(const bf16x8*)&sR1[o * ZT_S + kk * 32 + qd * 8];
                        acc = mfma16(aa[kk], bb, acc);
                    }
                    const float bias = fcb[o];
                    #pragma unroll
                    for (int r = 0; r < 4; ++r) acc[r] += bias;
                    oacc[j] = acc;
                }

                if (layer == 0) {
                    #pragma unroll
                    for (int r = 0; r < 4; ++r) {
                        float s = 0.f, s2 = 0.f;
                        #pragma unroll
                        for (int j = 0; j < 8; ++j) { const float vv = oacc[j][r]; s += vv; s2 += vv * vv; }
                        #pragma unroll
                        for (int m = 1; m <= 8; m <<= 1) { s += __shfl_xor(s, m); s2 += __shfl_xor(s2, m); }
                        if (l15 == 0) {
                            const int row = mb + qd * 4 + r;
                            atomicAdd(&sRed[row], s);
                            atomicAdd(&sRed[64 + row], s2);
                        }
                    }
                    __syncthreads();                       // b5
                    float mean4[4], rstd4[4];
                    #pragma unroll
                    for (int r = 0; r < 4; ++r) {
                        const int row = mb + qd * 4 + r;
                        const float mean = sRed[row] * (1.f / 256.f);
                        const float var  = sRed[64 + row] * (1.f / 256.f) - mean * mean;
                        mean4[r] = mean;
                        rstd4[r] = rsqrtf(var + 1e-5f);
                    }
                    #pragma unroll
                    for (int j = 0; j < 8; ++j) {
                        const int o = ng * 128 + j * 16 + l15;
                        const float g = ln0_g[o], bb = ln0_b[o];
                        #pragma unroll
                        for (int r = 0; r < 4; ++r) {
                            float y = (oacc[j][r] - mean4[r]) * rstd4[r] * g + bb;
                            y = (y >= 0.f) ? y : 0.1f * y;   // LeakyReLU(0.1)
                            sXn[(mb + qd * 4 + r) * XN_S + o] = (__bf16)y;
                        }
                    }
                    __syncthreads();                       // b6
                } else {
                    float* op = outp + (size_t)b * 16384;
                    #pragma unroll
                    for (int j = 0; j < 8; ++j) {
                        const int o = ng * 128 + j * 16 + l15;
                        #pragma unroll
                        for (int r = 0; r < 4; ++r)
                            op[(mb + qd * 4 + r) * 256 + o] = oacc[j][r];
                    }
                    // no barrier: next element's P1 only writes sXn/sRed (not read here)
                }
            }
        }
    }
}

extern "C" void kernel_launch(void* const* d_in, const int* in_sizes, int n_in,
                              void* d_out, int out_size, void* d_ws, size_t ws_size,
                              hipStream_t stream) {
    const float* graph   = (const float*)d_in[0];
    const float* ln_in_g = (const float*)d_in[1];
    const float* ln_in_b = (const float*)d_in[2];
    const float* adj0    = (const float*)d_in[3];
    const float* th0     = (const float*)d_in[4];
    const float* ph0     = (const float*)d_in[5];
    const float* fcw0    = (const float*)d_in[6];
    const float* fcb0    = (const float*)d_in[7];
    const float* ln0_g   = (const float*)d_in[8];
    const float* ln0_b   = (const float*)d_in[9];
    const float* adj1    = (const float*)d_in[10];
    const float* th1     = (const float*)d_in[11];
    const float* ph1     = (const float*)d_in[12];
    const float* fcw1    = (const float*)d_in[13];
    const float* fcb1    = (const float*)d_in[14];
    __bf16* wsb = (__bf16*)d_ws;

    prep_all<<<800, 256, 0, stream>>>(adj0, adj1, th0, ph0, th1, ph1, fcw0, fcw1, wsb);
    fused_gcn<<<512, 512, 0, stream>>>(graph, ln_in_g, ln_in_b, wsb,
                                       fcb0, ln0_g, ln0_b, fcb1, (float*)d_out);
}

// Round 3
// 478.933 us; speedup vs baseline: 1.0062x; 1.0062x over previous
//
#include <hip/hip_runtime.h>

typedef __bf16 bf16x8 __attribute__((ext_vector_type(8)));
typedef __bf16 bf16x4 __attribute__((ext_vector_type(4)));
typedef float  f32x4  __attribute__((ext_vector_type(4)));

// ---- workspace layout (in __bf16 elements) ----
constexpr int WS_AS0 = 0;        // A_static layer0: [64][64]
constexpr int WS_AS1 = 4096;     // A_static layer1
constexpr int WS_MT0 = 8192;     // MT0 = ph0^T@th0/sqrt(128), [256][256] bf16
constexpr int WS_MT1 = 73728;
constexpr int WS_FC0 = 139264;   // fc0 bf16 [256][256]
constexpr int WS_FC1 = 204800;   // end 270336 elems = 540672 B

static __device__ __forceinline__ f32x4 mfma16(bf16x8 a, bf16x8 b, f32x4 c) {
    return __builtin_amdgcn_mfma_f32_16x16x32_bf16(a, b, c, 0, 0, 0);
}

// ---------- single prep kernel: adj softmax | MT gemm | fc cast ----------
// grid: [0,32) adj rows (1 wave/row) | [32,544) MT (block=e,layer) | [544,800) fc
__global__ void prep_all(const float* __restrict__ adj0, const float* __restrict__ adj1,
                         const float* __restrict__ th0,  const float* __restrict__ ph0,
                         const float* __restrict__ th1,  const float* __restrict__ ph1,
                         const float* __restrict__ fc0,  const float* __restrict__ fc1,
                         __bf16* __restrict__ wsb) {
    const int blk = blockIdx.x, tid = threadIdx.x;
    if (blk < 32) {
        const int w = tid >> 6, lane = tid & 63;
        const int row = blk * 4 + w;              // 0..127
        const int layer = row >> 6, r = row & 63;
        const float* a = (layer ? adj1 : adj0) + r * 64;
        const float v = a[lane];
        float mx = v;
        #pragma unroll
        for (int m = 1; m < 64; m <<= 1) mx = fmaxf(mx, __shfl_xor(mx, m));
        float e = __expf(v - mx), sum = e;
        #pragma unroll
        for (int m = 1; m < 64; m <<= 1) sum += __shfl_xor(sum, m);
        wsb[(layer ? WS_AS1 : WS_AS0) + r * 64 + lane] = (__bf16)(e / sum);
    } else if (blk < 544) {
        const int e = (blk - 32) & 255, layer = (blk - 32) >> 8, d = tid;
        const float* th = layer ? th1 : th0;
        const float* ph = layer ? ph1 : ph0;
        float s = 0.f;
        #pragma unroll 8
        for (int h = 0; h < 128; ++h) s += ph[h * 256 + e] * th[h * 256 + d];
        wsb[(layer ? WS_MT1 : WS_MT0) + e * 256 + d] = (__bf16)(s * 0.088388347648318447f);
    } else {
        const int i = (blk - 544) * 512 + tid * 2;    // 0..131070 step 2
        if (i < 65536) {
            wsb[WS_FC0 + i]     = (__bf16)fc0[i];
            wsb[WS_FC0 + i + 1] = (__bf16)fc0[i + 1];
        } else {
            wsb[WS_FC1 + i - 65536] = (__bf16)fc1[i - 65536];
            wsb[WS_FC1 + i - 65535] = (__bf16)fc1[i - 65535];
        }
    }
}

// ---------- fused 2-layer GCN: persistent blocks, 4 batch elements each ----------
// grid 512 x 512 threads (8 waves), LDS 80384 B -> 2 blocks/CU, all-resident.
// amdgpu_waves_per_eu(4,4): LDS caps occupancy at 4 waves/EU anyway; pinning it
// lets the allocator use the full 128-VGPR budget instead of spilling the
// cross-barrier state (gv prefetch, zpk) to hold a useless 64-VGPR target.
// Per element: P1(LN from prefetched regs) | A(t+z merged per-jm, z in regs) |
// P3(scores/softmax) | zT-write (+prefetch next graph slice) | P5(A_hat@zT +
// LN/leaky or store).
__global__ __launch_bounds__(512) __attribute__((amdgpu_waves_per_eu(4, 4))) void fused_gcn(
    const float* __restrict__ graph,
    const float* __restrict__ ln_in_g, const float* __restrict__ ln_in_b,
    const __bf16* __restrict__ wsb,
    const float* __restrict__ fcb0, const float* __restrict__ ln0_g,
    const float* __restrict__ ln0_b, const float* __restrict__ fcb1,
    float* __restrict__ outp)
{
    constexpr int XN_S = 264;   // xn / t row stride (bf16), 528 B = 33*16B (odd granule)
    constexpr int ZT_S = 72;    // zT row stride: 144 B
    constexpr int AH_S = 72;    // A_hat row stride

    __shared__ __align__(16) __bf16 sXn[64 * XN_S];   // 33792 B  (xn, persistent per layer)
    __shared__ __align__(16) __bf16 sR1[256 * ZT_S];  // 36864 B  (t[64][XN_S], then zT[256][72])
    __shared__ __align__(16) __bf16 sAh[64 * AH_S];   //  9216 B  (As staged, then A_hat)
    __shared__ float sRed[128];                       //   512 B

    const int tid = threadIdx.x;
    const int w = tid >> 6, lane = tid & 63;
    const int l15 = lane & 15, qd = lane >> 4;
    const int r8 = tid >> 3, ci8 = (tid & 7) * 32;    // P1/prefetch row & col base

    // ---- prefetch element 0's graph slice into registers
    f32x4 gv[8];
    {
        const float* gp = graph + (size_t)blockIdx.x * 16384 + r8 * 256 + ci8;
        #pragma unroll
        for (int j = 0; j < 8; ++j) gv[j] = *(const f32x4*)(gp + j * 4);
    }

    #pragma unroll 1
    for (int it = 0; it < 4; ++it) {
        const int b = blockIdx.x + it * 512;

        // ---- P1: LayerNorm(graph[b]) -> sXn (bf16). 8 threads per row, from gv regs.
        {
            if (tid < 128) sRed[tid] = 0.f;
            float s = 0.f, s2 = 0.f;
            #pragma unroll
            for (int j = 0; j < 8; ++j)
                #pragma unroll
                for (int e = 0; e < 4; ++e) { s += gv[j][e]; s2 += gv[j][e] * gv[j][e]; }
            #pragma unroll
            for (int m = 1; m <= 4; m <<= 1) { s += __shfl_xor(s, m); s2 += __shfl_xor(s2, m); }
            const float mean = s * (1.f / 256.f);
            const float var  = s2 * (1.f / 256.f) - mean * mean;
            const float rstd = rsqrtf(var + 1e-5f);
            #pragma unroll
            for (int j = 0; j < 8; ++j) {
                f32x4 gg = *(const f32x4*)(ln_in_g + ci8 + j * 4);
                f32x4 bb = *(const f32x4*)(ln_in_b + ci8 + j * 4);
                bf16x4 pk;
                #pragma unroll
                for (int e = 0; e < 4; ++e)
                    pk[e] = (__bf16)((gv[j][e] - mean) * rstd * gg[e] + bb[e]);
                *(bf16x4*)&sXn[r8 * XN_S + ci8 + j * 4] = pk;
            }
        }
        __syncthreads();                                   // b1

        #pragma unroll 1
        for (int layer = 0; layer < 2; ++layer) {
            const __bf16* As  = wsb + (layer ? WS_AS1 : WS_AS0);
            const __bf16* mtw = wsb + (layer ? WS_MT1 : WS_MT0);
            const __bf16* fcw = wsb + (layer ? WS_FC1 : WS_FC0);
            const float*  fcb = layer ? fcb1 : fcb0;

            bf16x4 zpk[4][2];   // packed z slice, lives across the next two barriers

            // ---- Phase A: t = xn@M AND z = xn@fc^T sharing sXn reads, split by jm
            //      to cap register pressure. t -> sR1 (row-major t[node][e]);
            //      z stays in registers. Stage As -> sAh.
            {
                {   // stage A_static into sAh (one b128 per thread)
                    const int rr = tid >> 3, c8 = (tid & 7) * 8;
                    *(bf16x8*)&sAh[rr * AH_S + c8] = *(const bf16x8*)(As + rr * 64 + c8);
                }
                #pragma unroll
                for (int jm = 0; jm < 2; ++jm) {
                    const int row = w * 32 + jm * 16 + l15;   // e-row (mtw) == o-row (fcw)
                    f32x4 tacc[4], zacc[4];
                    #pragma unroll
                    for (int i = 0; i < 4; ++i) {
                        tacc[i] = (f32x4){0.f, 0.f, 0.f, 0.f};
                        zacc[i] = (f32x4){0.f, 0.f, 0.f, 0.f};
                    }
                    #pragma unroll
                    for (int kk = 0; kk < 8; ++kk) {
                        const int co = kk * 32 + qd * 8;
                        bf16x8 amt = *(const bf16x8*)(mtw + row * 256 + co);
                        bf16x8 afc = *(const bf16x8*)(fcw + row * 256 + co);
                        #pragma unroll
                        for (int nt = 0; nt < 4; ++nt) {
                            bf16x8 bx = *(const bf16x8*)&sXn[(nt * 16 + l15) * XN_S + co];
                            tacc[nt] = mfma16(amt, bx, tacc[nt]);   // C[e][node]
                            zacc[nt] = mfma16(bx, afc, zacc[nt]);   // C[node][o]
                        }
                    }
                    // write t row-major (lane holds 4 consecutive e at node nt*16+l15)
                    #pragma unroll
                    for (int nt = 0; nt < 4; ++nt) {
                        bf16x4 pk;
                        #pragma unroll
                        for (int r = 0; r < 4; ++r) pk[r] = (__bf16)tacc[nt][r];
                        *(bf16x4*)&sR1[(nt * 16 + l15) * XN_S + (w * 2 + jm) * 16 + qd * 4] = pk;
                    }
                    // pack z to bf16 regs (deferred LDS write until t is dead)
                    #pragma unroll
                    for (int nt = 0; nt < 4; ++nt)
                        #pragma unroll
                        for (int r = 0; r < 4; ++r)
                            zpk[nt][jm][r] = (__bf16)zacc[nt][r];
                }
            }
            __syncthreads();                               // b2

            // ---- P3 (waves 0-3): scores = t@xn^T (K=256) -> softmax -> +As
            if (w < 4) {
                const int mb = w * 16;
                bf16x8 at[8];
                #pragma unroll
                for (int kk = 0; kk < 8; ++kk)
                    at[kk] = *(const bf16x8*)&sR1[(mb + l15) * XN_S + kk * 32 + qd * 8];
                f32x4 sc[4];
                #pragma unroll
                for (int nt = 0; nt < 4; ++nt) sc[nt] = (f32x4){0.f, 0.f, 0.f, 0.f};
                #pragma unroll
                for (int nt = 0; nt < 4; ++nt)
                    #pragma unroll
                    for (int kk = 0; kk < 8; ++kk) {
                        bf16x8 bx = *(const bf16x8*)&sXn[(nt * 16 + l15) * XN_S + kk * 32 + qd * 8];
                        sc[nt] = mfma16(at[kk], bx, sc[nt]);
                    }
                #pragma unroll
                for (int r = 0; r < 4; ++r) {
                    float v[4];
                    #pragma unroll
                    for (int nt = 0; nt < 4; ++nt) v[nt] = sc[nt][r];
                    float mx = fmaxf(fmaxf(v[0], v[1]), fmaxf(v[2], v[3]));
                    #pragma unroll
                    for (int m = 1; m <= 8; m <<= 1) mx = fmaxf(mx, __shfl_xor(mx, m));
                    float e[4], sum = 0.f;
                    #pragma unroll
                    for (int nt = 0; nt < 4; ++nt) { e[nt] = __expf(v[nt] - mx); sum += e[nt]; }
                    #pragma unroll
                    for (int m = 1; m <= 8; m <<= 1) sum += __shfl_xor(sum, m);
                    const float inv = 1.f / sum;
                    const int row = mb + qd * 4 + r;
                    #pragma unroll
                    for (int nt = 0; nt < 4; ++nt) {
                        const int col = nt * 16 + l15;
                        const float as = (float)sAh[row * AH_S + col];   // staged As
                        sAh[row * AH_S + col] = (__bf16)(e[nt] * inv + as);
                    }
                }
            }
            __syncthreads();                               // b3 (t dead; zT region free)

            // ---- zT write from registers (all 8 waves) + next-element graph prefetch
            {
                #pragma unroll
                for (int jm = 0; jm < 2; ++jm) {
                    const int o = w * 32 + jm * 16 + l15;
                    #pragma unroll
                    for (int nt = 0; nt < 4; ++nt)
                        *(bf16x4*)&sR1[o * ZT_S + nt * 16 + qd * 4] = zpk[nt][jm];
                }
            }
            if (layer == 1 && it < 3) {
                const float* gp = graph + (size_t)(b + 512) * 16384 + r8 * 256 + ci8;
                #pragma unroll
                for (int j = 0; j < 8; ++j) gv[j] = *(const f32x4*)(gp + j * 4);
            }
            __syncthreads();                               // b4

            // ---- P5: out = A_hat @ zT + fcb; fused LN+leaky (layer0) or store.
            {
                const int mb = (w & 3) * 16, ng = w >> 2;
                bf16x8 aa[2];
                #pragma unroll
                for (int kk = 0; kk < 2; ++kk)
                    aa[kk] = *(const bf16x8*)&sAh[(mb + l15) * AH_S + kk * 32 + qd * 8];
                f32x4 oacc[8];
                #pragma unroll
                for (int j = 0; j < 8; ++j) {
                    const int o = ng * 128 + j * 16 + l15;
                    f32x4 acc = {0.f, 0.f, 0.f, 0.f};
                    #pragma unroll
                    for (int kk = 0; kk < 2; ++kk) {
                        bf16x8 bb = *(const bf16x8*)&sR1[o * ZT_S + kk * 32 + qd * 8];
                        acc = mfma16(aa[kk], bb, acc);
                    }
                    const float bias = fcb[o];
                    #pragma unroll
                    for (int r = 0; r < 4; ++r) acc[r] += bias;
                    oacc[j] = acc;
                }

                if (layer == 0) {
                    #pragma unroll
                    for (int r = 0; r < 4; ++r) {
                        float s = 0.f, s2 = 0.f;
                        #pragma unroll
                        for (int j = 0; j < 8; ++j) { const float vv = oacc[j][r]; s += vv; s2 += vv * vv; }
                        #pragma unroll
                        for (int m = 1; m <= 8; m <<= 1) { s += __shfl_xor(s, m); s2 += __shfl_xor(s2, m); }
                        if (l15 == 0) {
                            const int row = mb + qd * 4 + r;
                            atomicAdd(&sRed[row], s);
                            atomicAdd(&sRed[64 + row], s2);
                        }
                    }
                    __syncthreads();                       // b5
                    float mean4[4], rstd4[4];
                    #pragma unroll
                    for (int r = 0; r < 4; ++r) {
                        const int row = mb + qd * 4 + r;
                        const float mean = sRed[row] * (1.f / 256.f);
                        const float var  = sRed[64 + row] * (1.f / 256.f) - mean * mean;
                        mean4[r] = mean;
                        rstd4[r] = rsqrtf(var + 1e-5f);
                    }
                    #pragma unroll
                    for (int j = 0; j < 8; ++j) {
                        const int o = ng * 128 + j * 16 + l15;
                        const float g = ln0_g[o], bb = ln0_b[o];
                        #pragma unroll
                        for (int r = 0; r < 4; ++r) {
                            float y = (oacc[j][r] - mean4[r]) * rstd4[r] * g + bb;
                            y = (y >= 0.f) ? y : 0.1f * y;   // LeakyReLU(0.1)
                            sXn[(mb + qd * 4 + r) * XN_S + o] = (__bf16)y;
                        }
                    }
                    __syncthreads();                       // b6
                } else {
                    float* op = outp + (size_t)b * 16384;
                    #pragma unroll
                    for (int j = 0; j < 8; ++j) {
                        const int o = ng * 128 + j * 16 + l15;
                        #pragma unroll
                        for (int r = 0; r < 4; ++r)
                            op[(mb + qd * 4 + r) * 256 + o] = oacc[j][r];
                    }
                    // no barrier: next element's P1 only writes sXn/sRed (not read here)
                }
            }
        }
    }
}

extern "C" void kernel_launch(void* const* d_in, const int* in_sizes, int n_in,
                              void* d_out, int out_size, void* d_ws, size_t ws_size,
                              hipStream_t stream) {
    const float* graph   = (const float*)d_in[0];
    const float* ln_in_g = (const float*)d_in[1];
    const float* ln_in_b = (const float*)d_in[2];
    const float* adj0    = (const float*)d_in[3];
    const float* th0     = (const float*)d_in[4];
    const float* ph0     = (const float*)d_in[5];
    const float* fcw0    = (const float*)d_in[6];
    const float* fcb0    = (const float*)d_in[7];
    const float* ln0_g   = (const float*)d_in[8];
    const float* ln0_b   = (const float*)d_in[9];
    const float* adj1    = (const float*)d_in[10];
    const float* th1     = (const float*)d_in[11];
    const float* ph1     = (const float*)d_in[12];
    const float* fcw1    = (const float*)d_in[13];
    const float* fcb1    = (const float*)d_in[14];
    __bf16* wsb = (__bf16*)d_ws;

    prep_all<<<800, 256, 0, stream>>>(adj0, adj1, th0, ph0, th1, ph1, fcw0, fcw1, wsb);
    fused_gcn<<<512, 512, 0, stream>>>(graph, ln_in_g, ln_in_b, wsb,
                                       fcb0, ln0_g, ln0_b, fcb1, (float*)d_out);
}

// Round 4
// 399.747 us; speedup vs baseline: 1.2055x; 1.1981x over previous
//
#include <hip/hip_runtime.h>

typedef __bf16 bf16x8 __attribute__((ext_vector_type(8)));
typedef __bf16 bf16x4 __attribute__((ext_vector_type(4)));
typedef float  f32x4  __attribute__((ext_vector_type(4)));

// ---- workspace layout (in __bf16 elements) ----
constexpr int WS_AS0 = 0;        // A_static layer0: [64][64]
constexpr int WS_AS1 = 4096;     // A_static layer1
constexpr int WS_MT0 = 8192;     // MT0 = ph0^T@th0/sqrt(128), [256][256] bf16
constexpr int WS_MT1 = 73728;
constexpr int WS_FC0 = 139264;   // fc0 bf16 [256][256]
constexpr int WS_FC1 = 204800;   // end 270336 elems = 540672 B

static __device__ __forceinline__ f32x4 mfma16(bf16x8 a, bf16x8 b, f32x4 c) {
    return __builtin_amdgcn_mfma_f32_16x16x32_bf16(a, b, c, 0, 0, 0);
}

// ---------- single prep kernel: adj softmax | MT gemm | fc cast ----------
// grid: [0,32) adj rows (1 wave/row) | [32,544) MT (block=e,layer) | [544,800) fc
__global__ void prep_all(const float* __restrict__ adj0, const float* __restrict__ adj1,
                         const float* __restrict__ th0,  const float* __restrict__ ph0,
                         const float* __restrict__ th1,  const float* __restrict__ ph1,
                         const float* __restrict__ fc0,  const float* __restrict__ fc1,
                         __bf16* __restrict__ wsb) {
    const int blk = blockIdx.x, tid = threadIdx.x;
    if (blk < 32) {
        const int w = tid >> 6, lane = tid & 63;
        const int row = blk * 4 + w;              // 0..127
        const int layer = row >> 6, r = row & 63;
        const float* a = (layer ? adj1 : adj0) + r * 64;
        const float v = a[lane];
        float mx = v;
        #pragma unroll
        for (int m = 1; m < 64; m <<= 1) mx = fmaxf(mx, __shfl_xor(mx, m));
        float e = __expf(v - mx), sum = e;
        #pragma unroll
        for (int m = 1; m < 64; m <<= 1) sum += __shfl_xor(sum, m);
        wsb[(layer ? WS_AS1 : WS_AS0) + r * 64 + lane] = (__bf16)(e / sum);
    } else if (blk < 544) {
        const int e = (blk - 32) & 255, layer = (blk - 32) >> 8, d = tid;
        const float* th = layer ? th1 : th0;
        const float* ph = layer ? ph1 : ph0;
        float s = 0.f;
        #pragma unroll 8
        for (int h = 0; h < 128; ++h) s += ph[h * 256 + e] * th[h * 256 + d];
        wsb[(layer ? WS_MT1 : WS_MT0) + e * 256 + d] = (__bf16)(s * 0.088388347648318447f);
    } else {
        const int i = (blk - 544) * 512 + tid * 2;    // 0..131070 step 2
        if (i < 65536) {
            wsb[WS_FC0 + i]     = (__bf16)fc0[i];
            wsb[WS_FC0 + i + 1] = (__bf16)fc0[i + 1];
        } else {
            wsb[WS_FC1 + i - 65536] = (__bf16)fc1[i - 65536];
            wsb[WS_FC1 + i - 65535] = (__bf16)fc1[i - 65535];
        }
    }
}

// ---------- fused 2-layer GCN: one block per batch element ----------
// 512 threads = 8 waves. LDS 80384 B -> 2 blocks/CU.
// Phase discipline: NO large register state crosses any __syncthreads()
// (the allocator's 64-VGPR budget is immovable; >~32 crossing regs spill).
// PT and PZ use 2-jm A-operand blocking: one sXn ds_read_b128 feeds 2 MFMAs,
// halving LDS read traffic vs the 1:1 baseline.
__global__ __launch_bounds__(512, 4) void fused_gcn(
    const float* __restrict__ graph,
    const float* __restrict__ ln_in_g, const float* __restrict__ ln_in_b,
    const __bf16* __restrict__ wsb,
    const float* __restrict__ fcb0, const float* __restrict__ ln0_g,
    const float* __restrict__ ln0_b, const float* __restrict__ fcb1,
    float* __restrict__ outp)
{
    constexpr int XN_S = 264;   // xn / t row stride (bf16)
    constexpr int ZT_S = 72;    // zT row stride: 144 B, 16B-aligned -> b128 reads
    constexpr int AH_S = 72;    // A_hat row stride

    __shared__ __align__(16) __bf16 sXn[64 * XN_S];   // 33792 B  (xn, persistent per layer)
    __shared__ __align__(16) __bf16 sR1[256 * ZT_S];  // 36864 B  (t[64][.]@XN_S, then zT[256][72])
    __shared__ __align__(16) __bf16 sAh[64 * AH_S];   //  9216 B  (As staged, then A_hat)
    __shared__ float sRed[128];                       //   512 B

    const int tid = threadIdx.x;
    const int w = tid >> 6, lane = tid & 63;
    const int l15 = lane & 15, qd = lane >> 4;
    const int b = blockIdx.x;

    // ---- P1: LayerNorm(graph[b]) -> sXn (bf16). 8 threads per row.
    {
        if (tid < 128) sRed[tid] = 0.f;
        const int r = tid >> 3, ci = (tid & 7) * 32;
        const float* gp = graph + (size_t)b * 16384 + r * 256 + ci;
        f32x4 v[8];
        float s = 0.f, s2 = 0.f;
        #pragma unroll
        for (int j = 0; j < 8; ++j) {
            v[j] = *(const f32x4*)(gp + j * 4);
            #pragma unroll
            for (int e = 0; e < 4; ++e) { s += v[j][e]; s2 += v[j][e] * v[j][e]; }
        }
        #pragma unroll
        for (int m = 1; m <= 4; m <<= 1) { s += __shfl_xor(s, m); s2 += __shfl_xor(s2, m); }
        const float mean = s * (1.f / 256.f);
        const float var  = s2 * (1.f / 256.f) - mean * mean;
        const float rstd = rsqrtf(var + 1e-5f);
        #pragma unroll
        for (int j = 0; j < 8; ++j) {
            f32x4 gg = *(const f32x4*)(ln_in_g + ci + j * 4);
            f32x4 bb = *(const f32x4*)(ln_in_b + ci + j * 4);
            bf16x4 pk;
            #pragma unroll
            for (int e = 0; e < 4; ++e)
                pk[e] = (__bf16)((v[j][e] - mean) * rstd * gg[e] + bb[e]);
            *(bf16x4*)&sXn[r * XN_S + ci + j * 4] = pk;
        }
    }
    __syncthreads();

    #pragma unroll 1
    for (int layer = 0; layer < 2; ++layer) {
        const __bf16* As  = wsb + (layer ? WS_AS1 : WS_AS0);
        const __bf16* mtw = wsb + (layer ? WS_MT1 : WS_MT0);
        const __bf16* fcw = wsb + (layer ? WS_FC1 : WS_FC0);
        const float*  fcb = layer ? fcb1 : fcb0;

        // ---- PT: t = xn @ M, 2-jm blocked: each bx read feeds 2 MFMAs.
        //      Also stage As -> sAh.
        {
            {   // stage A_static into sAh (one b128 per thread)
                const int r = tid >> 3, c8 = (tid & 7) * 8;
                *(bf16x8*)&sAh[r * AH_S + c8] = *(const bf16x8*)(As + r * 64 + c8);
            }
            const int row0 = w * 32 + l15;        // e-rows: jm0 = row0, jm1 = row0+16
            f32x4 tacc[2][4];
            #pragma unroll
            for (int i = 0; i < 4; ++i) {
                tacc[0][i] = (f32x4){0.f, 0.f, 0.f, 0.f};
                tacc[1][i] = (f32x4){0.f, 0.f, 0.f, 0.f};
            }
            #pragma unroll
            for (int kk = 0; kk < 8; ++kk) {
                const int co = kk * 32 + qd * 8;
                bf16x8 amt0 = *(const bf16x8*)(mtw + row0 * 256 + co);
                bf16x8 amt1 = *(const bf16x8*)(mtw + (row0 + 16) * 256 + co);
                #pragma unroll
                for (int nt = 0; nt < 4; ++nt) {
                    bf16x8 bx = *(const bf16x8*)&sXn[(nt * 16 + l15) * XN_S + co];
                    tacc[0][nt] = mfma16(amt0, bx, tacc[0][nt]);   // C[e][node]
                    tacc[1][nt] = mfma16(amt1, bx, tacc[1][nt]);
                }
            }
            // write t row-major (lane holds 4 consecutive e at node nt*16+l15)
            #pragma unroll
            for (int jm = 0; jm < 2; ++jm)
                #pragma unroll
                for (int nt = 0; nt < 4; ++nt) {
                    bf16x4 pk;
                    #pragma unroll
                    for (int r = 0; r < 4; ++r) pk[r] = (__bf16)tacc[jm][nt][r];
                    *(bf16x4*)&sR1[(nt * 16 + l15) * XN_S + (w * 2 + jm) * 16 + qd * 4] = pk;
                }
        }
        __syncthreads();

        // ---- P3 (waves 0-3): scores = t@xn^T (K=256) -> softmax -> +As (from LDS)
        if (w < 4) {
            const int mb = w * 16;
            bf16x8 at[8];
            #pragma unroll
            for (int kk = 0; kk < 8; ++kk)
                at[kk] = *(const bf16x8*)&sR1[(mb + l15) * XN_S + kk * 32 + qd * 8];
            f32x4 sc[4];
            #pragma unroll
            for (int nt = 0; nt < 4; ++nt) sc[nt] = (f32x4){0.f, 0.f, 0.f, 0.f};
            #pragma unroll
            for (int nt = 0; nt < 4; ++nt)
                #pragma unroll
                for (int kk = 0; kk < 8; ++kk) {
                    bf16x8 bx = *(const bf16x8*)&sXn[(nt * 16 + l15) * XN_S + kk * 32 + qd * 8];
                    sc[nt] = mfma16(at[kk], bx, sc[nt]);
                }
            #pragma unroll
            for (int r = 0; r < 4; ++r) {
                float v[4];
                #pragma unroll
                for (int nt = 0; nt < 4; ++nt) v[nt] = sc[nt][r];
                float mx = fmaxf(fmaxf(v[0], v[1]), fmaxf(v[2], v[3]));
                #pragma unroll
                for (int m = 1; m <= 8; m <<= 1) mx = fmaxf(mx, __shfl_xor(mx, m));
                float e[4], sum = 0.f;
                #pragma unroll
                for (int nt = 0; nt < 4; ++nt) { e[nt] = __expf(v[nt] - mx); sum += e[nt]; }
                #pragma unroll
                for (int m = 1; m <= 8; m <<= 1) sum += __shfl_xor(sum, m);
                const float inv = 1.f / sum;
                const int row = mb + qd * 4 + r;
                #pragma unroll
                for (int nt = 0; nt < 4; ++nt) {
                    const int col = nt * 16 + l15;
                    const float as = (float)sAh[row * AH_S + col];   // staged As
                    sAh[row * AH_S + col] = (__bf16)(e[nt] * inv + as);
                }
            }
        }
        __syncthreads();   // t dead; zT region free

        // ---- PZ (all 8 waves): z = xn@fc^T, 2-jm blocked: each ax read feeds
        //      2 MFMAs. Written straight to zT. No registers survive the barrier.
        {
            const int o0 = w * 32 + l15;          // o-rows: jm0 = o0, jm1 = o0+16
            f32x4 zacc[4][2];
            #pragma unroll
            for (int m = 0; m < 4; ++m) {
                zacc[m][0] = (f32x4){0.f, 0.f, 0.f, 0.f};
                zacc[m][1] = (f32x4){0.f, 0.f, 0.f, 0.f};
            }
            #pragma unroll
            for (int kk = 0; kk < 8; ++kk) {
                const int co = kk * 32 + qd * 8;
                bf16x8 afc0 = *(const bf16x8*)(fcw + o0 * 256 + co);
                bf16x8 afc1 = *(const bf16x8*)(fcw + (o0 + 16) * 256 + co);
                #pragma unroll
                for (int m = 0; m < 4; ++m) {
                    bf16x8 ax = *(const bf16x8*)&sXn[(m * 16 + l15) * XN_S + co];
                    zacc[m][0] = mfma16(ax, afc0, zacc[m][0]);   // C[node][o]
                    zacc[m][1] = mfma16(ax, afc1, zacc[m][1]);
                }
            }
            #pragma unroll
            for (int jm = 0; jm < 2; ++jm) {
                const int o = w * 32 + jm * 16 + l15;
                #pragma unroll
                for (int m = 0; m < 4; ++m) {
                    bf16x4 pk;
                    #pragma unroll
                    for (int r = 0; r < 4; ++r) pk[r] = (__bf16)zacc[m][jm][r];
                    *(bf16x4*)&sR1[o * ZT_S + m * 16 + qd * 4] = pk;
                }
            }
        }
        __syncthreads();

        // ---- P5: out = A_hat @ zT + fcb; fused LN+leaky (layer0) or store.
        {
            const int mb = (w & 3) * 16, ng = w >> 2;
            bf16x8 aa[2];
            #pragma unroll
            for (int kk = 0; kk < 2; ++kk)
                aa[kk] = *(const bf16x8*)&sAh[(mb + l15) * AH_S + kk * 32 + qd * 8];
            f32x4 oacc[8];
            #pragma unroll
            for (int j = 0; j < 8; ++j) {
                const int o = ng * 128 + j * 16 + l15;
                f32x4 acc = {0.f, 0.f, 0.f, 0.f};
                #pragma unroll
                for (int kk = 0; kk < 2; ++kk) {
                    bf16x8 bb = *(const bf16x8*)&sR1[o * ZT_S + kk * 32 + qd * 8];
                    acc = mfma16(aa[kk], bb, acc);
                }
                const float bias = fcb[o];
                #pragma unroll
                for (int r = 0; r < 4; ++r) acc[r] += bias;
                oacc[j] = acc;
            }

            if (layer == 0) {
                #pragma unroll
                for (int r = 0; r < 4; ++r) {
                    float s = 0.f, s2 = 0.f;
                    #pragma unroll
                    for (int j = 0; j < 8; ++j) { const float vv = oacc[j][r]; s += vv; s2 += vv * vv; }
                    #pragma unroll
                    for (int m = 1; m <= 8; m <<= 1) { s += __shfl_xor(s, m); s2 += __shfl_xor(s2, m); }
                    if (l15 == 0) {
                        const int row = mb + qd * 4 + r;
                        atomicAdd(&sRed[row], s);
                        atomicAdd(&sRed[64 + row], s2);
                    }
                }
                __syncthreads();
                float mean4[4], rstd4[4];
                #pragma unroll
                for (int r = 0; r < 4; ++r) {
                    const int row = mb + qd * 4 + r;
                    const float mean = sRed[row] * (1.f / 256.f);
                    const float var  = sRed[64 + row] * (1.f / 256.f) - mean * mean;
                    mean4[r] = mean;
                    rstd4[r] = rsqrtf(var + 1e-5f);
                }
                #pragma unroll
                for (int j = 0; j < 8; ++j) {
                    const int o = ng * 128 + j * 16 + l15;
                    const float g = ln0_g[o], bb = ln0_b[o];
                    #pragma unroll
                    for (int r = 0; r < 4; ++r) {
                        float y = (oacc[j][r] - mean4[r]) * rstd4[r] * g + bb;
                        y = (y >= 0.f) ? y : 0.1f * y;   // LeakyReLU(0.1)
                        sXn[(mb + qd * 4 + r) * XN_S + o] = (__bf16)y;
                    }
                }
                __syncthreads();
            } else {
                float* op = outp + (size_t)b * 16384;
                #pragma unroll
                for (int j = 0; j < 8; ++j) {
                    const int o = ng * 128 + j * 16 + l15;
                    #pragma unroll
                    for (int r = 0; r < 4; ++r)
                        op[(mb + qd * 4 + r) * 256 + o] = oacc[j][r];
                }
            }
        }
    }
}

extern "C" void kernel_launch(void* const* d_in, const int* in_sizes, int n_in,
                              void* d_out, int out_size, void* d_ws, size_t ws_size,
                              hipStream_t stream) {
    const float* graph   = (const float*)d_in[0];
    const float* ln_in_g = (const float*)d_in[1];
    const float* ln_in_b = (const float*)d_in[2];
    const float* adj0    = (const float*)d_in[3];
    const float* th0     = (const float*)d_in[4];
    const float* ph0     = (const float*)d_in[5];
    const float* fcw0    = (const float*)d_in[6];
    const float* fcb0    = (const float*)d_in[7];
    const float* ln0_g   = (const float*)d_in[8];
    const float* ln0_b   = (const float*)d_in[9];
    const float* adj1    = (const float*)d_in[10];
    const float* th1     = (const float*)d_in[11];
    const float* ph1     = (const float*)d_in[12];
    const float* fcw1    = (const float*)d_in[13];
    const float* fcb1    = (const float*)d_in[14];
    __bf16* wsb = (__bf16*)d_ws;

    prep_all<<<800, 256, 0, stream>>>(adj0, adj1, th0, ph0, th1, ph1, fcw0, fcw1, wsb);
    fused_gcn<<<2048, 512, 0, stream>>>(graph, ln_in_g, ln_in_b, wsb,
                                        fcb0, ln0_g, ln0_b, fcb1, (float*)d_out);
}